// Round 1
// baseline (582.905 us; speedup 1.0000x reference)
//
#include <hip/hip_runtime.h>

// Weighted segment-sum (graph attention aggregate), sorted segment_ids.
// out[n,f] = sum_{e in [start_n, end_n)} att[e] * neigh[e,f] + bias[f]
//
// One wave (64 lanes) per output node. segment_ids sorted -> each node's
// edges are contiguous; binary search finds the range, so NO atomics and
// each output row is written exactly once (coalesced float4 store).
//
// Vectorization: a wave consumes 4 edge-rows per iteration with float4
// loads: lane l covers row (e + l/16), columns 4*(l&15)..+3 -> 64 lanes
// x 16B = 1024B contiguous = 4 full rows. Reduce the 4 row-groups with
// two shfl_down steps (stride 32, 16); lanes 0..15 hold the final row.

#define N_NODES 50000
#define N_EDGES 1600000
#define FEAT 64

__global__ __launch_bounds__(256) void segsum_kernel(
    const float* __restrict__ neigh,   // [E, 64]
    const float* __restrict__ att,     // [E]
    const float* __restrict__ bias,    // [64]
    const int*   __restrict__ seg,     // [E], sorted
    float* __restrict__ out,           // [N, 64]
    int n_edges, int n_nodes)
{
    const int wave_id = (blockIdx.x * blockDim.x + threadIdx.x) >> 6;
    const int lane    = threadIdx.x & 63;
    if (wave_id >= n_nodes) return;
    const int node = wave_id;

    // Branchless-ish lower_bound: even lanes search `node`, odd lanes
    // `node+1`; broadcast both results. seg[] is hot in L2/L3.
    {
    }
    const int target = node + (lane & 1);
    int lo = 0, hi = n_edges;
    while (lo < hi) {
        const int mid = (lo + hi) >> 1;
        if (seg[mid] < target) lo = mid + 1; else hi = mid;
    }
    const int start = __shfl(lo, 0);
    const int end   = __shfl(lo, 1);

    const int rowgrp = lane >> 4;        // 0..3: which of the 4 rows
    const int colgrp = lane & 15;        // columns 4*colgrp .. +3

    float4 acc = make_float4(0.f, 0.f, 0.f, 0.f);

    int e = start;
    // Main loop: 4 rows (1024B) per iteration, 16B/lane float4 loads.
    for (; e + 4 <= end; e += 4) {
        const int r = e + rowgrp;
        const float a = att[r];
        const float4 v = *(const float4*)(neigh + (size_t)r * FEAT + colgrp * 4);
        acc.x = fmaf(a, v.x, acc.x);
        acc.y = fmaf(a, v.y, acc.y);
        acc.z = fmaf(a, v.z, acc.z);
        acc.w = fmaf(a, v.w, acc.w);
    }
    // Tail: up to 3 remaining rows, predicated per row-group.
    if (e + rowgrp < end) {
        const int r = e + rowgrp;
        const float a = att[r];
        const float4 v = *(const float4*)(neigh + (size_t)r * FEAT + colgrp * 4);
        acc.x = fmaf(a, v.x, acc.x);
        acc.y = fmaf(a, v.y, acc.y);
        acc.z = fmaf(a, v.z, acc.z);
        acc.w = fmaf(a, v.w, acc.w);
    }

    // Reduce the 4 row-groups (lanes l, l+16, l+32, l+48) down to lanes 0..15.
    #pragma unroll
    for (int off = 32; off >= 16; off >>= 1) {
        acc.x += __shfl_down(acc.x, off);
        acc.y += __shfl_down(acc.y, off);
        acc.z += __shfl_down(acc.z, off);
        acc.w += __shfl_down(acc.w, off);
    }

    if (rowgrp == 0) {
        const float4 b = *(const float4*)(bias + colgrp * 4);
        float4 o;
        o.x = acc.x + b.x;
        o.y = acc.y + b.y;
        o.z = acc.z + b.z;
        o.w = acc.w + b.w;
        *(float4*)(out + (size_t)node * FEAT + colgrp * 4) = o;
    }
}

extern "C" void kernel_launch(void* const* d_in, const int* in_sizes, int n_in,
                              void* d_out, int out_size, void* d_ws, size_t ws_size,
                              hipStream_t stream) {
    // Inputs (setup_inputs order): nodes [N,64] (UNUSED by reference),
    // neighbor_feats [E,64], attention [E], bias [64], segment_ids [E].
    const float* neigh = (const float*)d_in[1];
    const float* att   = (const float*)d_in[2];
    const float* bias  = (const float*)d_in[3];
    const int*   seg   = (const int*)d_in[4];
    float* out = (float*)d_out;

    const int n_edges = in_sizes[2];           // attention is [E]
    const int n_nodes = out_size / FEAT;       // 50000

    const int waves_per_block = 256 / 64;      // 4 nodes per block
    const int blocks = (n_nodes + waves_per_block - 1) / waves_per_block;
    segsum_kernel<<<blocks, 256, 0, stream>>>(neigh, att, bias, seg, out,
                                              n_edges, n_nodes);
}

// Round 2
// 546.708 us; speedup vs baseline: 1.0662x; 1.0662x over previous
//
#include <hip/hip_runtime.h>

// Weighted segment-sum (graph attention aggregate), sorted segment_ids.
// out[n,f] = sum_{e in [offs[n], offs[n+1])} att[e] * neigh[e,f] + bias[f]
//
// R2: replace the per-wave 21-level binary search (21 DEPENDENT global
// loads) with a precomputed offsets array: kernel 1 scans seg[] once
// (coalesced, ~13 MB) and writes offs[n] = lower_bound(seg, n) for all n;
// kernel 2 reads its [start,end) range with 2 loads. Main loop unrolled
// x2 (8 rows / 2048 B per iter, two independent float4 loads + two
// accumulators) to keep 2 VMEM ops in flight per wave.

#define FEAT 64

// ---- kernel 1: segment boundaries -----------------------------------------
__global__ __launch_bounds__(256) void boundaries_kernel(
    const int* __restrict__ seg,   // [E], sorted
    int* __restrict__ offs,        // [N+1]
    int n_edges, int n_nodes)
{
    const int e = blockIdx.x * blockDim.x + threadIdx.x;
    if (e >= n_edges) return;
    const int s = seg[e];
    if (e == 0) {
        for (int n = 0; n <= s; ++n) offs[n] = 0;
    } else {
        const int sp = seg[e - 1];
        if (sp != s)
            for (int n = sp + 1; n <= s; ++n) offs[n] = e;
    }
    if (e == n_edges - 1) {
        for (int n = s + 1; n <= n_nodes; ++n) offs[n] = n_edges;
    }
}

// ---- kernel 2: one wave per node, gather + weighted sum -------------------
__global__ __launch_bounds__(256) void segsum_kernel(
    const float* __restrict__ neigh,   // [E, 64]
    const float* __restrict__ att,     // [E]
    const float* __restrict__ bias,    // [64]
    const int*   __restrict__ offs,    // [N+1]
    float* __restrict__ out,           // [N, 64]
    int n_nodes)
{
    const int wave_id = (blockIdx.x * blockDim.x + threadIdx.x) >> 6;
    const int lane    = threadIdx.x & 63;
    if (wave_id >= n_nodes) return;
    const int node = wave_id;

    const int start = offs[node];
    const int end   = offs[node + 1];

    const int rowgrp = lane >> 4;        // 0..3: which row of the 4-row group
    const int colgrp = lane & 15;        // columns 4*colgrp .. +3

    float4 acc0 = make_float4(0.f, 0.f, 0.f, 0.f);
    float4 acc1 = make_float4(0.f, 0.f, 0.f, 0.f);

    int e = start;
    // 8 rows (2048 B) per iteration: two independent 16 B/lane loads.
    for (; e + 8 <= end; e += 8) {
        const int r0 = e + rowgrp;
        const int r1 = e + 4 + rowgrp;
        const float  a0 = att[r0];
        const float4 v0 = *(const float4*)(neigh + (size_t)r0 * FEAT + colgrp * 4);
        const float  a1 = att[r1];
        const float4 v1 = *(const float4*)(neigh + (size_t)r1 * FEAT + colgrp * 4);
        acc0.x = fmaf(a0, v0.x, acc0.x);
        acc0.y = fmaf(a0, v0.y, acc0.y);
        acc0.z = fmaf(a0, v0.z, acc0.z);
        acc0.w = fmaf(a0, v0.w, acc0.w);
        acc1.x = fmaf(a1, v1.x, acc1.x);
        acc1.y = fmaf(a1, v1.y, acc1.y);
        acc1.z = fmaf(a1, v1.z, acc1.z);
        acc1.w = fmaf(a1, v1.w, acc1.w);
    }
    // 4-row step.
    if (e + 4 <= end) {
        const int r = e + rowgrp;
        const float  a = att[r];
        const float4 v = *(const float4*)(neigh + (size_t)r * FEAT + colgrp * 4);
        acc0.x = fmaf(a, v.x, acc0.x);
        acc0.y = fmaf(a, v.y, acc0.y);
        acc0.z = fmaf(a, v.z, acc0.z);
        acc0.w = fmaf(a, v.w, acc0.w);
        e += 4;
    }
    // Tail: up to 3 rows, predicated per row-group.
    if (e + rowgrp < end) {
        const int r = e + rowgrp;
        const float  a = att[r];
        const float4 v = *(const float4*)(neigh + (size_t)r * FEAT + colgrp * 4);
        acc1.x = fmaf(a, v.x, acc1.x);
        acc1.y = fmaf(a, v.y, acc1.y);
        acc1.z = fmaf(a, v.z, acc1.z);
        acc1.w = fmaf(a, v.w, acc1.w);
    }

    float4 acc;
    acc.x = acc0.x + acc1.x;
    acc.y = acc0.y + acc1.y;
    acc.z = acc0.z + acc1.z;
    acc.w = acc0.w + acc1.w;

    // Fold the 4 row-groups (lanes l, l+16, l+32, l+48) into lanes 0..15.
    #pragma unroll
    for (int off = 32; off >= 16; off >>= 1) {
        acc.x += __shfl_down(acc.x, off);
        acc.y += __shfl_down(acc.y, off);
        acc.z += __shfl_down(acc.z, off);
        acc.w += __shfl_down(acc.w, off);
    }

    if (rowgrp == 0) {
        const float4 b = *(const float4*)(bias + colgrp * 4);
        float4 o;
        o.x = acc.x + b.x;
        o.y = acc.y + b.y;
        o.z = acc.z + b.z;
        o.w = acc.w + b.w;
        *(float4*)(out + (size_t)node * FEAT + colgrp * 4) = o;
    }
}

extern "C" void kernel_launch(void* const* d_in, const int* in_sizes, int n_in,
                              void* d_out, int out_size, void* d_ws, size_t ws_size,
                              hipStream_t stream) {
    // Inputs (setup_inputs order): nodes [N,64] (UNUSED by reference),
    // neighbor_feats [E,64], attention [E], bias [64], segment_ids [E].
    const float* neigh = (const float*)d_in[1];
    const float* att   = (const float*)d_in[2];
    const float* bias  = (const float*)d_in[3];
    const int*   seg   = (const int*)d_in[4];
    float* out = (float*)d_out;

    const int n_edges = in_sizes[2];           // attention is [E]
    const int n_nodes = out_size / FEAT;       // 50000

    int* offs = (int*)d_ws;                    // (N+1) ints, d_ws is plenty

    boundaries_kernel<<<(n_edges + 255) / 256, 256, 0, stream>>>(
        seg, offs, n_edges, n_nodes);

    const int waves_per_block = 256 / 64;      // 4 nodes per block
    const int blocks = (n_nodes + waves_per_block - 1) / waves_per_block;
    segsum_kernel<<<blocks, 256, 0, stream>>>(neigh, att, bias, offs, out,
                                              n_nodes);
}